// Round 4
// baseline (556.816 us; speedup 1.0000x reference)
//
#include <hip/hip_runtime.h>
#include <math.h>

#define NN 50000
#define NE 800000
#define NFD 256
#define HD 64
#define QDD 128
#define TDD 32
#define NTT 64
#define NLAY 3
#define LCLAMP 6.1030340f   // atanh(1 - 1e-5)
#define CHUNK 1024
#define NCHUNK 49           // ceil(50000/1024)

typedef unsigned int uint;
typedef unsigned short ushort;

__device__ __forceinline__ ushort f2bf(float f) {
  uint u = __float_as_uint(f);
  uint r = (u + 0x7FFFu + ((u >> 16) & 1u)) >> 16;
  return (ushort)r;
}
__device__ __forceinline__ float bflo(uint w) { return __uint_as_float(w << 16); }
__device__ __forceinline__ float bfhi(uint w) { return __uint_as_float(w & 0xFFFF0000u); }

__device__ __forceinline__ float bfly_sum(float v) {
  v += __shfl_xor(v, 1, 64);
  v += __shfl_xor(v, 2, 64);
  v += __shfl_xor(v, 4, 64);
  v += __shfl_xor(v, 8, 64);
  v += __shfl_xor(v, 16, 64);
  v += __shfl_xor(v, 32, 64);
  return v;
}

// ---------------------------------------------------------------- setup (small dense precomputes)
__global__ void k_setup(const float* __restrict__ edge_desc, const float* __restrict__ query,
                        const float* __restrict__ Wq, const float* __restrict__ bq,
                        const float* __restrict__ Ws, const float* __restrict__ bs,
                        const float* __restrict__ attn_a,
                        const float* __restrict__ Wns1, const float* __restrict__ bns1,
                        const float* __restrict__ Wes1, const float* __restrict__ bes1,
                        float* __restrict__ out_type_emb,
                        float* __restrict__ qb, float* __restrict__ ta3,
                        float* __restrict__ Te2) {
  __shared__ float te_l[NTT * TDD];
  __shared__ float q_l[HD];
  __shared__ float qe_l[HD];
  int t = threadIdx.x;
  if (t < HD) {
    float acc = bq[t];
    for (int k = 0; k < QDD; ++k) acc += query[k] * Wq[k * HD + t];
    q_l[t] = acc;
  }
  for (int idx = t; idx < NTT * TDD; idx += 256) {
    int ty = idx / TDD, d = idx % TDD;
    float acc = bs[d];
    for (int k = 0; k < 64; ++k) acc += edge_desc[ty * 64 + k] * Ws[k * TDD + d];
    float v = tanhf(acc);
    te_l[idx] = v;
    out_type_emb[idx] = v;
  }
  __syncthreads();
  if (t < NLAY * NTT) {
    int l = t / NTT, ty = t % NTT;
    float acc = 0.f;
    for (int d = 0; d < TDD; ++d) acc += te_l[ty * TDD + d] * attn_a[l * (2 * HD + TDD) + 2 * HD + d];
    ta3[t] = acc;
  }
  if (t < HD) {
    float a1 = bns1[t], a2 = bes1[t];
    for (int k = 0; k < HD; ++k) {
      a1 += q_l[k] * Wns1[(HD + k) * HD + t];
      a2 += q_l[k] * Wes1[(2 * HD + TDD + k) * HD + t];
    }
    qb[t] = a1;
    qe_l[t] = a2;
  }
  __syncthreads();
  for (int idx = t; idx < NTT * HD; idx += 256) {
    int ty = idx >> 6, j = idx & 63;
    float acc = qe_l[j];
    for (int d = 0; d < TDD; ++d) acc += te_l[ty * TDD + d] * Wes1[(2 * HD + d) * HD + j];
    Te2[idx] = acc;
  }
}

// ---------------------------------------------------------------- CSR build
__global__ void k_hist(const int* __restrict__ dst, int* __restrict__ cnt) {
  int e = blockIdx.x * 256 + threadIdx.x;
  if (e < NE) atomicAdd(&cnt[dst[e]], 1);
}

__global__ void k_scanA(const int* __restrict__ cnt, int* __restrict__ bsum) {
  __shared__ int ws[4];
  int t = threadIdx.x;
  int c0 = blockIdx.x * CHUNK;
  int s = 0;
#pragma unroll
  for (int it = 0; it < 4; ++it) {
    int i = c0 + it * 256 + t;
    if (i < NN) s += cnt[i];
  }
#pragma unroll
  for (int off = 1; off < 64; off <<= 1) s += __shfl_xor(s, off, 64);
  if ((t & 63) == 0) ws[t >> 6] = s;
  __syncthreads();
  if (t == 0) bsum[blockIdx.x] = ws[0] + ws[1] + ws[2] + ws[3];
}

__global__ void k_scanB(const int* __restrict__ bsum, int* __restrict__ boff,
                        int* __restrict__ row_ptr) {
  int t = threadIdx.x;  // 64 threads
  int v = (t < NCHUNK) ? bsum[t] : 0;
  int x = v;
#pragma unroll
  for (int off = 1; off < 64; off <<= 1) {
    int y = __shfl_up(x, off, 64);
    if (t >= off) x += y;
  }
  if (t < NCHUNK) boff[t] = x - v;
  if (t == 63) row_ptr[NN] = x;
}

__global__ void k_scanC(const int* __restrict__ cnt, const int* __restrict__ boff,
                        int* __restrict__ row_ptr, int* __restrict__ cursor) {
  __shared__ int wsum[4], woff_s[4];
  int t = threadIdx.x;
  int c0 = blockIdx.x * CHUNK;
  int i0 = c0 + t * 4;
  int v0 = (i0 + 0 < NN) ? cnt[i0 + 0] : 0;
  int v1 = (i0 + 1 < NN) ? cnt[i0 + 1] : 0;
  int v2 = (i0 + 2 < NN) ? cnt[i0 + 2] : 0;
  int v3 = (i0 + 3 < NN) ? cnt[i0 + 3] : 0;
  int s4 = v0 + v1 + v2 + v3;
  int lane = t & 63, wid = t >> 6;
  int x = s4;
#pragma unroll
  for (int off = 1; off < 64; off <<= 1) {
    int y = __shfl_up(x, off, 64);
    if (lane >= off) x += y;
  }
  if (lane == 63) wsum[wid] = x;
  __syncthreads();
  if (t == 0) {
    int a = 0;
    for (int i = 0; i < 4; ++i) { woff_s[i] = a; a += wsum[i]; }
  }
  __syncthreads();
  int base = boff[blockIdx.x] + woff_s[wid] + (x - s4);
  int r0 = base, r1 = base + v0, r2 = r1 + v1, r3 = r2 + v2;
  if (i0 + 0 < NN) { row_ptr[i0 + 0] = r0; cursor[i0 + 0] = r0; }
  if (i0 + 1 < NN) { row_ptr[i0 + 1] = r1; cursor[i0 + 1] = r1; }
  if (i0 + 2 < NN) { row_ptr[i0 + 2] = r2; cursor[i0 + 2] = r2; }
  if (i0 + 3 < NN) { row_ptr[i0 + 3] = r3; cursor[i0 + 3] = r3; }
}

__global__ void k_scatter(const int* __restrict__ src, const int* __restrict__ dst,
                          const int* __restrict__ etype, int* __restrict__ cursor,
                          uint* __restrict__ csr) {
  int e = blockIdx.x * 256 + threadIdx.x;
  if (e < NE) {
    int d = dst[e];
    int pos = atomicAdd(&cursor[d], 1);
    csr[pos] = (uint)src[e] | ((uint)etype[e] << 16);
  }
}

// ---------------------------------------------------------------- initial projection
// ht0 = clamp_norm((X @ Wn + bn) * ts).  lane = output col j; weights in VGPR;
// activations stream through SGPRs (wave-uniform row addresses). 4 waves split K=256.
__global__ void __launch_bounds__(256) k_proj(const float* __restrict__ X,
                                              const float* __restrict__ Wn,
                                              const float* __restrict__ bn,
                                              const float* __restrict__ ts_p,
                                              float* __restrict__ ht0) {
  __shared__ float ps[16][4][64];  // 16 KB partials
  int t = threadIdx.x;
  int lane = t & 63;
  int wv = t >> 6;
  int n0 = blockIdx.x * 64;
  float wcol[64];
#pragma unroll
  for (int k = 0; k < 64; ++k) wcol[k] = Wn[(wv * 64 + k) * HD + lane];
  float vbn = bn[lane];
  float ts = ts_p[0];

  for (int batch = 0; batch < 4; ++batch) {
    int b0 = n0 + batch * 16;
#pragma unroll 4
    for (int i = 0; i < 16; ++i) {
      int m = b0 + i;
      if (m < NN) {
        const float* ar = X + (size_t)__builtin_amdgcn_readfirstlane(m * NFD + wv * 64);
        float acc = 0.f;
#pragma unroll
        for (int k = 0; k < 64; ++k) acc = fmaf(ar[k], wcol[k], acc);
        ps[i][wv][lane] = acc;
      }
    }
    __syncthreads();
#pragma unroll
    for (int ii = 0; ii < 4; ++ii) {
      int i = wv * 4 + ii;
      int m = b0 + i;
      if (m < NN) {
        float v = ps[i][0][lane] + ps[i][1][lane] + ps[i][2][lane] + ps[i][3][lane];
        v = (v + vbn) * ts;
        float ssq = bfly_sum(v * v);
        float nu = fmaxf(sqrtf(ssq), 1e-15f);
        float sc = fminf(nu, LCLAMP) / nu;
        ht0[(size_t)m * HD + lane] = v * sc;
      }
    }
    __syncthreads();
  }
}

// ---------------------------------------------------------------- msg = ht @ Wmp + bmp (bf16); p_src/p_dst
// lane = output col; each wave streams 16 nodes.
__global__ void __launch_bounds__(256) k_msg(const float* __restrict__ ht,
                                             const float* __restrict__ Wmp_l,
                                             const float* __restrict__ bmp_l,
                                             const float* __restrict__ attn_l,
                                             ushort* __restrict__ msgbf,
                                             float* __restrict__ p_src,
                                             float* __restrict__ p_dst) {
  int t = threadIdx.x;
  int lane = t & 63;
  int wv = t >> 6;
  int n0 = blockIdx.x * 64 + wv * 16;
  float wcol[64];
#pragma unroll
  for (int k = 0; k < 64; ++k) wcol[k] = Wmp_l[k * HD + lane];
  float vb = bmp_l[lane];
  float va1 = attn_l[lane];
  float va2 = attn_l[HD + lane];

#pragma unroll 4
  for (int i = 0; i < 16; ++i) {
    int m = n0 + i;
    if (m >= NN) break;
    int mu = __builtin_amdgcn_readfirstlane(m);
    const float* ar = ht + (size_t)mu * HD;
    float va = ar[lane];          // coalesced vector row copy (for the reduces)
    float acc = vb;
#pragma unroll
    for (int k = 0; k < 64; ++k) acc = fmaf(ar[k], wcol[k], acc);
    float r1 = bfly_sum(va * va1);
    float r2 = bfly_sum(va * va2);
    if (lane == 0) { p_src[mu] = r1; p_dst[mu] = r2; }
    msgbf[(size_t)mu * HD + lane] = f2bf(acc);
  }
}

// ---------------------------------------------------------------- softmax-aggregate (wave/node, 8-wide gather)
__global__ void __launch_bounds__(256) k_agg(const int* __restrict__ row_ptr,
                                             const uint* __restrict__ csr,
                                             const float* __restrict__ p_src,
                                             const float* __restrict__ p_dst,
                                             const float* __restrict__ ta_l,
                                             const ushort* __restrict__ msgbf,
                                             float* __restrict__ ht_out,
                                             float* __restrict__ s_buf) {
  int lane = threadIdx.x & 63;
  int n = (blockIdx.x * 256 + threadIdx.x) >> 6;
  if (n >= NN) return;
  int start = row_ptr[n], end = row_ptr[n + 1];
  int deg = end - start;
  float pd = p_dst[n];
  int lq = lane & 7, lg = lane >> 3;
  float acc[8];
#pragma unroll
  for (int u = 0; u < 8; ++u) acc[u] = 0.f;
  float exsum = 0.f;

  if (deg <= 64) {
    bool valid = lane < deg;
    float s = -3.4e38f;
    int sidx = 0;
    if (valid) {
      uint pk = csr[start + lane];
      sidx = (int)(pk & 0xFFFFu);
      int ty = (int)(pk >> 16);
      float v = p_src[sidx] + pd + ta_l[ty];
      s = (v > 0.f) ? v : 0.2f * v;
    }
    float m = s;
#pragma unroll
    for (int off = 32; off >= 1; off >>= 1) m = fmaxf(m, __shfl_xor(m, off, 64));
    float ex = valid ? __expf(s - m) : 0.f;
    exsum = ex;
    for (int it = 0; it < deg; it += 8) {
      int el = it + lg;
      float exk = __shfl(ex, el, 64);
      int sk = __shfl(sidx, el, 64);
      if (el < deg) {
        uint4 mv = *(const uint4*)&msgbf[(size_t)sk * HD + lq * 8];
        acc[0] += exk * bflo(mv.x); acc[1] += exk * bfhi(mv.x);
        acc[2] += exk * bflo(mv.y); acc[3] += exk * bfhi(mv.y);
        acc[4] += exk * bflo(mv.z); acc[5] += exk * bfhi(mv.z);
        acc[6] += exk * bflo(mv.w); acc[7] += exk * bfhi(mv.w);
      }
    }
  } else {
    float m = -3.4e38f;
    for (int base = start; base < end; base += 64) {
      int i = base + lane;
      float s = -3.4e38f;
      if (i < end) {
        uint pk = csr[i];
        int sidx = (int)(pk & 0xFFFFu);
        int ty = (int)(pk >> 16);
        float v = p_src[sidx] + pd + ta_l[ty];
        s = (v > 0.f) ? v : 0.2f * v;
        s_buf[i] = s;
      }
      m = fmaxf(m, s);
    }
#pragma unroll
    for (int off = 32; off >= 1; off >>= 1) m = fmaxf(m, __shfl_xor(m, off, 64));
    for (int base = start; base < end; base += 64) {
      int i = base + lane;
      if (i < end) {
        float ex = __expf(s_buf[i] - m);
        s_buf[i] = ex;
        exsum += ex;
      }
    }
    for (int it = start; it < end; it += 8) {
      int el = it + lg;
      if (el < end) {
        float exk = s_buf[el];
        int sk = (int)(csr[el] & 0xFFFFu);
        uint4 mv = *(const uint4*)&msgbf[(size_t)sk * HD + lq * 8];
        acc[0] += exk * bflo(mv.x); acc[1] += exk * bfhi(mv.x);
        acc[2] += exk * bflo(mv.y); acc[3] += exk * bfhi(mv.y);
        acc[4] += exk * bflo(mv.z); acc[5] += exk * bfhi(mv.z);
        acc[6] += exk * bflo(mv.w); acc[7] += exk * bfhi(mv.w);
      }
    }
  }
#pragma unroll
  for (int u = 0; u < 8; ++u) {
    acc[u] += __shfl_xor(acc[u], 8, 64);
    acc[u] += __shfl_xor(acc[u], 16, 64);
    acc[u] += __shfl_xor(acc[u], 32, 64);
  }
#pragma unroll
  for (int off = 32; off >= 1; off >>= 1) exsum += __shfl_xor(exsum, off, 64);
  float inv = 1.f / (exsum + 1e-15f);
  float ss = 0.f;
#pragma unroll
  for (int u = 0; u < 8; ++u) {
    float v = fmaxf(acc[u] * inv, 0.f);
    acc[u] = v;
    ss += v * v;
  }
  ss += __shfl_xor(ss, 1, 64);
  ss += __shfl_xor(ss, 2, 64);
  ss += __shfl_xor(ss, 4, 64);
  float nu = fmaxf(sqrtf(ss), 1e-15f);
  float sc = fminf(nu, LCLAMP) / nu;
  if (lane < 8) {
    *(float4*)&ht_out[(size_t)n * HD + lane * 8] =
        make_float4(acc[0] * sc, acc[1] * sc, acc[2] * sc, acc[3] * sc);
    *(float4*)&ht_out[(size_t)n * HD + lane * 8 + 4] =
        make_float4(acc[4] * sc, acc[5] * sc, acc[6] * sc, acc[7] * sc);
  }
}

// ---------------------------------------------------------------- heads (wave-specialized):
// wv0: node head (Wns1/qb/Wns2 -> node_scores); wv1: Asrc; wv2: Adst; wv3: h_out
__global__ void __launch_bounds__(256) k_score(const float* __restrict__ ht,
                                               const float* __restrict__ Wns1,
                                               const float* __restrict__ qb,
                                               const float* __restrict__ Wns2,
                                               const float* __restrict__ bns2,
                                               const float* __restrict__ Wes1,
                                               float* __restrict__ node_scores,
                                               float* __restrict__ h_out,
                                               ushort* __restrict__ Asrc,
                                               ushort* __restrict__ Adst) {
  int t = threadIdx.x;
  int lane = t & 63;
  int wv = t >> 6;
  int n0 = blockIdx.x * 64;

  if (wv == 0) {
    float wcol[64];
#pragma unroll
    for (int k = 0; k < 64; ++k) wcol[k] = Wns1[k * HD + lane];
    float vqb = qb[lane];
    float vw2 = Wns2[lane];
    float b2 = bns2[0];
#pragma unroll 4
    for (int i = 0; i < 64; ++i) {
      int m = n0 + i;
      if (m >= NN) break;
      int mu = __builtin_amdgcn_readfirstlane(m);
      const float* ar = ht + (size_t)mu * HD;
      float acc = 0.f;
#pragma unroll
      for (int k = 0; k < 64; ++k) acc = fmaf(ar[k], wcol[k], acc);
      float z = fmaxf(acc + vqb, 0.f) * vw2;
      float logit = bfly_sum(z) + b2;
      if (lane == 0) node_scores[mu] = 1.f / (1.f + __expf(-logit));
    }
  } else if (wv == 1) {
    float wcol[64];
#pragma unroll
    for (int k = 0; k < 64; ++k) wcol[k] = Wes1[k * HD + lane];
#pragma unroll 4
    for (int i = 0; i < 64; ++i) {
      int m = n0 + i;
      if (m >= NN) break;
      int mu = __builtin_amdgcn_readfirstlane(m);
      const float* ar = ht + (size_t)mu * HD;
      float acc = 0.f;
#pragma unroll
      for (int k = 0; k < 64; ++k) acc = fmaf(ar[k], wcol[k], acc);
      Asrc[(size_t)mu * HD + lane] = f2bf(acc);
    }
  } else if (wv == 2) {
    float wcol[64];
#pragma unroll
    for (int k = 0; k < 64; ++k) wcol[k] = Wes1[(HD + k) * HD + lane];
#pragma unroll 4
    for (int i = 0; i < 64; ++i) {
      int m = n0 + i;
      if (m >= NN) break;
      int mu = __builtin_amdgcn_readfirstlane(m);
      const float* ar = ht + (size_t)mu * HD;
      float acc = 0.f;
#pragma unroll
      for (int k = 0; k < 64; ++k) acc = fmaf(ar[k], wcol[k], acc);
      Adst[(size_t)mu * HD + lane] = f2bf(acc);
    }
  } else {
#pragma unroll 4
    for (int i = 0; i < 64; ++i) {
      int m = n0 + i;
      if (m >= NN) break;
      int mu = __builtin_amdgcn_readfirstlane(m);
      float va = ht[(size_t)mu * HD + lane];
      float ssq = bfly_sum(va * va);
      float nu = fmaxf(sqrtf(ssq), 1e-15f);
      float hs = tanhf(nu) / nu;
      h_out[(size_t)mu * HD + lane] = va * hs;
    }
  }
}

// ---------------------------------------------------------------- edge scores (8 lanes/edge, 8 edges/wave)
__global__ void __launch_bounds__(256) k_edge(const int* __restrict__ src,
                                              const int* __restrict__ dst,
                                              const int* __restrict__ etype,
                                              const ushort* __restrict__ Asrc,
                                              const ushort* __restrict__ Adst,
                                              const float* __restrict__ Te2,
                                              const float* __restrict__ Wes2,
                                              const float* __restrict__ bes2,
                                              float* __restrict__ edge_scores) {
  int t = threadIdx.x;
  int lane = t & 63;
  int lq = lane & 7, lg = lane >> 3;
  int w = (blockIdx.x * 256 + t) >> 6;
  int e = w * 8 + lg;
  float p = 0.f;
  if (e < NE) {
    int si = src[e], di = dst[e], ti = etype[e];
    uint4 av = *(const uint4*)&Asrc[(size_t)si * HD + lq * 8];
    uint4 bv = *(const uint4*)&Adst[(size_t)di * HD + lq * 8];
    const float* tp = &Te2[ti * HD + lq * 8];
    float4 t0 = *(const float4*)tp;
    float4 t1 = *(const float4*)(tp + 4);
    const float* wp = &Wes2[lq * 8];
    float4 w0 = *(const float4*)wp;
    float4 w1 = *(const float4*)(wp + 4);
    p += fmaxf(bflo(av.x) + bflo(bv.x) + t0.x, 0.f) * w0.x;
    p += fmaxf(bfhi(av.x) + bfhi(bv.x) + t0.y, 0.f) * w0.y;
    p += fmaxf(bflo(av.y) + bflo(bv.y) + t0.z, 0.f) * w0.z;
    p += fmaxf(bfhi(av.y) + bfhi(bv.y) + t0.w, 0.f) * w0.w;
    p += fmaxf(bflo(av.z) + bflo(bv.z) + t1.x, 0.f) * w1.x;
    p += fmaxf(bfhi(av.z) + bfhi(bv.z) + t1.y, 0.f) * w1.y;
    p += fmaxf(bflo(av.w) + bflo(bv.w) + t1.z, 0.f) * w1.z;
    p += fmaxf(bfhi(av.w) + bfhi(bv.w) + t1.w, 0.f) * w1.w;
  }
  p += __shfl_xor(p, 1, 64);
  p += __shfl_xor(p, 2, 64);
  p += __shfl_xor(p, 4, 64);
  if (e < NE && lq == 0) edge_scores[e] = 1.f / (1.f + __expf(-(p + bes2[0])));
}

// ---------------------------------------------------------------- launch
extern "C" void kernel_launch(void* const* d_in, const int* in_sizes, int n_in,
                              void* d_out, int out_size, void* d_ws, size_t ws_size,
                              hipStream_t stream) {
  const float* node_features = (const float*)d_in[0];
  const float* edge_desc = (const float*)d_in[1];
  const float* query = (const float*)d_in[2];
  const float* Wn = (const float*)d_in[3];
  const float* bn = (const float*)d_in[4];
  const float* ts = (const float*)d_in[5];
  const float* Wq = (const float*)d_in[6];
  const float* bq = (const float*)d_in[7];
  const float* Ws_ = (const float*)d_in[8];
  const float* bs = (const float*)d_in[9];
  const float* attn_a = (const float*)d_in[10];
  const float* Wmp = (const float*)d_in[11];
  const float* bmp = (const float*)d_in[12];
  const float* Wns1 = (const float*)d_in[13];
  const float* bns1 = (const float*)d_in[14];
  const float* Wns2 = (const float*)d_in[15];
  const float* bns2 = (const float*)d_in[16];
  const float* Wes1 = (const float*)d_in[17];
  const float* bes1 = (const float*)d_in[18];
  const float* Wes2 = (const float*)d_in[19];
  const float* bes2 = (const float*)d_in[20];
  const int* edge_index = (const int*)d_in[21];
  const int* etype = (const int*)d_in[22];
  const int* src = edge_index;
  const int* dst = edge_index + NE;

  float* out_ns = (float*)d_out;
  float* out_es = out_ns + NN;
  float* out_h = out_es + NE;
  float* out_te = out_h + (size_t)NN * HD;

  char* w = (char*)d_ws;
  auto alloc = [&](size_t bytes) {
    char* p = w;
    w += (bytes + 1023) & ~(size_t)1023;
    return p;
  };
  float* ht_a = (float*)alloc((size_t)NN * HD * 4);
  float* ht_b = (float*)alloc((size_t)NN * HD * 4);
  ushort* msgbf = (ushort*)alloc((size_t)NN * HD * 2);
  ushort* Asrc = (ushort*)alloc((size_t)NN * HD * 2);
  ushort* Adst = (ushort*)alloc((size_t)NN * HD * 2);
  float* p_src = (float*)alloc(NN * 4);
  float* p_dst = (float*)alloc(NN * 4);
  float* s_buf = (float*)alloc(NE * 4);
  float* qb = (float*)alloc(HD * 4);
  float* ta3 = (float*)alloc(NLAY * NTT * 4);
  float* Te2 = (float*)alloc(NTT * HD * 4);
  int* cnt = (int*)alloc(NN * 4);
  int* row_ptr = (int*)alloc((NN + 1) * 4);
  int* cursor = (int*)alloc(NN * 4);
  int* bsum = (int*)alloc(NCHUNK * 4);
  int* boff = (int*)alloc(NCHUNK * 4);
  uint* csr = (uint*)alloc(NE * 4);

  hipMemsetAsync(cnt, 0, NN * 4, stream);
  k_setup<<<1, 256, 0, stream>>>(edge_desc, query, Wq, bq, Ws_, bs, attn_a, Wns1, bns1,
                                 Wes1, bes1, out_te, qb, ta3, Te2);
  k_hist<<<NE / 256, 256, 0, stream>>>(dst, cnt);
  k_scanA<<<NCHUNK, 256, 0, stream>>>(cnt, bsum);
  k_scanB<<<1, 64, 0, stream>>>(bsum, boff, row_ptr);
  k_scanC<<<NCHUNK, 256, 0, stream>>>(cnt, boff, row_ptr, cursor);
  k_scatter<<<NE / 256, 256, 0, stream>>>(src, dst, etype, cursor, csr);
  k_proj<<<(NN + 63) / 64, 256, 0, stream>>>(node_features, Wn, bn, ts, ht_a);

  float* cur = ht_a;
  float* nxt = ht_b;
  for (int l = 0; l < NLAY; ++l) {
    k_msg<<<(NN + 63) / 64, 256, 0, stream>>>(cur, Wmp + l * HD * HD, bmp + l * HD,
                                              attn_a + l * (2 * HD + TDD), msgbf, p_src, p_dst);
    k_agg<<<(NN + 3) / 4, 256, 0, stream>>>(row_ptr, csr, p_src, p_dst, ta3 + l * NTT,
                                            msgbf, nxt, s_buf);
    float* tmp = cur; cur = nxt; nxt = tmp;
  }
  k_score<<<(NN + 63) / 64, 256, 0, stream>>>(cur, Wns1, qb, Wns2, bns2, Wes1,
                                              out_ns, out_h, Asrc, Adst);
  // 8 edges/wave, 4 waves/block => 32 edges per block
  k_edge<<<(NE + 31) / 32, 256, 0, stream>>>(src, dst, etype, Asrc, Adst, Te2,
                                             Wes2, bes2, out_es);
}